// Round 4
// baseline (413.998 us; speedup 1.0000x reference)
//
#include <hip/hip_runtime.h>
#include <math.h>

// ---------------------------------------------------------------------------
// Restormer-style TransformerBlock on MI355X (gfx950)
// B=4, C=192, H=W=128, N=HW=16384, heads=8, ch/head=24, hidden=510
// bf16 intermediates in [B][N][C]; residual path: x fp32 [C][N] (input),
// out1 bf16 [N][192], final d_out fp32 [C][N].
// ---------------------------------------------------------------------------

typedef __attribute__((ext_vector_type(8))) short short8;
typedef __attribute__((ext_vector_type(4))) short short4v;
typedef __attribute__((ext_vector_type(4))) float f32x4;

#define DEVI __device__ __forceinline__

DEVI unsigned short f2bf(float f) {
  union { float f; unsigned u; } v; v.f = f;
  unsigned r = v.u + 0x7fffu + ((v.u >> 16) & 1u);   // RNE
  return (unsigned short)(r >> 16);
}
DEVI float bf2f(unsigned short h) {
  union { unsigned u; float f; } v; v.u = ((unsigned)h) << 16;
  return v.f;
}

// ---------------------------------------------------------------------------
// K0: convert + zero-pad weights to bf16; pack dw-conv weights fp32.
//  wq [576][192]  = qkv_w
//  wi [1024][192] : rows 0..509 = ffn_in 0..509; 510,511 = 0;
//                   512..1021 = ffn_in 510..1019; 1022,1023 = 0
//  wo [192][512]  : cols >=510 zero
//  dwq [144][9][4] f32 : qkv_dw_w repacked (group of 4 ch per tap)
//  dwf [2][128][9][4] f32 : ffn_dw_w set0 rows c, set1 rows 510+c (c>=510 -> 0)
// ---------------------------------------------------------------------------
__global__ __launch_bounds__(256) void k_convert_w(
    const float* __restrict__ qkv_w, const float* __restrict__ ffn_in_w,
    const float* __restrict__ ffn_out_w, const float* __restrict__ qkv_dw_w,
    const float* __restrict__ ffn_dw_w,
    unsigned short* __restrict__ wq, unsigned short* __restrict__ wi,
    unsigned short* __restrict__ wo, float* __restrict__ dwq,
    float* __restrict__ dwf) {
  int idx = blockIdx.x * 256 + threadIdx.x;
  if (idx < 576 * 192) wq[idx] = f2bf(qkv_w[idx]);
  if (idx < 1024 * 192) {
    int o = idx / 192, c = idx - o * 192;
    int src = (o < 510) ? o : ((o >= 512 && o < 1022) ? o - 2 : -1);
    wi[idx] = (src >= 0) ? f2bf(ffn_in_w[src * 192 + c]) : (unsigned short)0;
  }
  if (idx < 192 * 512) {
    int o = idx >> 9, c = idx & 511;
    wo[idx] = (c < 510) ? f2bf(ffn_out_w[o * 510 + c]) : (unsigned short)0;
  }
  if (idx < 144 * 36) {
    int g = idx / 36, r = idx - g * 36;
    int q = r >> 2, j = r & 3;
    dwq[idx] = qkv_dw_w[(g * 4 + j) * 9 + q];
  }
  if (idx < 2 * 128 * 36) {
    int s = idx / (128 * 36);
    int rem = idx - s * 128 * 36;
    int g = rem / 36, r = rem - g * 36;
    int q = r >> 2, j = r & 3;
    int ch = g * 4 + j;
    dwf[idx] = (ch < 510) ? ffn_dw_w[(s ? 510 + ch : ch) * 9 + q] : 0.f;
  }
}

__global__ __launch_bounds__(256) void k_zero(float* __restrict__ p, int n) {
  int i = blockIdx.x * 256 + threadIdx.x;
  if (i < n) p[i] = 0.f;
}

// ---------------------------------------------------------------------------
// LN2: fp32 [B][192][N] -> bf16 [B][N][192]
// ---------------------------------------------------------------------------
__global__ __launch_bounds__(256) void k_ln(
    const float* __restrict__ x, const float* __restrict__ g,
    const float* __restrict__ bta, unsigned short* __restrict__ y) {
  int idx = blockIdx.x * 256 + threadIdx.x;   // 2 * B*N = 131072
  int half = idx & 1;
  int n = idx >> 1;
  int b = n >> 14, nn = n & 16383;
  int c0 = half * 96;
  const float* px = x + (((size_t)b * 192 + c0) << 14) + nn;
  float v[96];
  float s = 0.f, ss = 0.f;
#pragma unroll
  for (int j = 0; j < 96; j++) {
    v[j] = px[(size_t)j << 14];
    s += v[j]; ss += v[j] * v[j];
  }
  s += __shfl_xor(s, 1, 64);
  ss += __shfl_xor(ss, 1, 64);
  float mu = s * (1.f / 192.f);
  float var = ss * (1.f / 192.f) - mu * mu;
  float rs = rsqrtf(var + 1e-5f);
  unsigned short* py = y + ((((size_t)b << 14) + nn) * 192) + c0;
#pragma unroll
  for (int j8 = 0; j8 < 12; j8++) {
    short8 o8;
#pragma unroll
    for (int k = 0; k < 8; k++) {
      int c = c0 + j8 * 8 + k;
      o8[k] = (short)f2bf((v[j8 * 8 + k] - mu) * rs * g[c] + bta[c]);
    }
    *reinterpret_cast<short8*>(py + j8 * 8) = o8;
  }
}

// ---------------------------------------------------------------------------
// LN3: bf16 [B*N][192] -> bf16 [B*N][192]   (contiguous rows)
// ---------------------------------------------------------------------------
__global__ __launch_bounds__(256) void k_ln_bf(
    const unsigned short* __restrict__ in, const float* __restrict__ g,
    const float* __restrict__ bta, unsigned short* __restrict__ out) {
  int n = blockIdx.x * 256 + threadIdx.x;    // 65536
  const unsigned short* p = in + (size_t)n * 192;
  short8 raw[24];
  float s = 0.f, ss = 0.f;
#pragma unroll
  for (int j = 0; j < 24; j++) {
    raw[j] = *reinterpret_cast<const short8*>(p + j * 8);
#pragma unroll
    for (int k = 0; k < 8; k++) {
      float f = bf2f((unsigned short)raw[j][k]);
      s += f; ss += f * f;
    }
  }
  float mu = s * (1.f / 192.f);
  float var = ss * (1.f / 192.f) - mu * mu;
  float rs = rsqrtf(var + 1e-5f);
  unsigned short* q = out + (size_t)n * 192;
#pragma unroll
  for (int j = 0; j < 24; j++) {
    short8 o8;
#pragma unroll
    for (int k = 0; k < 8; k++) {
      int c = j * 8 + k;
      float f = bf2f((unsigned short)raw[j][k]);
      o8[k] = (short)f2bf((f - mu) * rs * g[c] + bta[c]);
    }
    *reinterpret_cast<short8*>(q + j * 8) = o8;
  }
}

// ---------------------------------------------------------------------------
// GEMM: out[o][n] = sum_c W[o][c] * in[n][c]
//  EPI 0: bf16 store to out[N][rsout] at col
//  EPI 2: bf16 store to out[N][192]: f2bf(residF[(b*192+o)<<14|nn] + acc)
//  EPI 3: fp32 store d_out[(b*192+o)<<14|nn] = bf2f(residB[n*192+o]) + acc
// ---------------------------------------------------------------------------
template <int C, int OCHUNK, int NB, int EPI>
__global__ __launch_bounds__(512) void k_gemm(
    const unsigned short* __restrict__ in, int rsin,
    const unsigned short* __restrict__ W, int wbs,
    const float* __restrict__ residF, const unsigned short* __restrict__ residB,
    void* __restrict__ outp, int rsout) {
  constexpr int SLOTS = C / 8;
  __shared__ unsigned short lds[OCHUNK * C];
  int t = threadIdx.x;
  int b = blockIdx.z;
  int ocb = blockIdx.y * OCHUNK;
  int wv = t >> 6, lane = t & 63, lrow = lane & 15, lhi = lane >> 4;

  const unsigned short* Wb = W + (size_t)b * wbs;
#pragma unroll
  for (int i = t; i < OCHUNK * SLOTS; i += 512) {
    int o = i / SLOTS, s = i - o * SLOTS;
    short8 v = *reinterpret_cast<const short8*>(&Wb[(size_t)(ocb + o) * C + s * 8]);
    *reinterpret_cast<short8*>(&lds[(o * SLOTS + (s ^ (o & 7))) * 8]) = v;
  }

  size_t nbase = ((size_t)b << 14) + blockIdx.x * (128 * NB) + wv * (16 * NB);
  short8 bf[NB][C / 32];
#pragma unroll
  for (int nb = 0; nb < NB; nb++) {
    const unsigned short* prow = in + (nbase + nb * 16 + lrow) * rsin + lhi * 8;
#pragma unroll
    for (int k = 0; k < C / 32; k++)
      bf[nb][k] = *reinterpret_cast<const short8*>(prow + k * 32);
  }
  __syncthreads();

  for (int ot = 0; ot < OCHUNK / 16; ++ot) {
    f32x4 acc[NB];
#pragma unroll
    for (int nb = 0; nb < NB; nb++) acc[nb] = (f32x4){0.f, 0.f, 0.f, 0.f};
    int orow = ot * 16 + lrow;
#pragma unroll
    for (int k = 0; k < C / 32; k++) {
      short8 a = *reinterpret_cast<const short8*>(
          &lds[(orow * SLOTS + ((k * 4 + lhi) ^ (lrow & 7))) * 8]);
#pragma unroll
      for (int nb = 0; nb < NB; nb++)
        acc[nb] = __builtin_amdgcn_mfma_f32_16x16x32_bf16(a, bf[nb][k], acc[nb], 0, 0, 0);
    }
#pragma unroll
    for (int nb = 0; nb < NB; nb++) {
      size_t n = nbase + nb * 16 + lrow;   // includes b*16384
      int obase = ocb + ot * 16 + lhi * 4;
      if (EPI == 0) {
        short4v pk;
#pragma unroll
        for (int r = 0; r < 4; r++) pk[r] = (short)f2bf(acc[nb][r]);
        *reinterpret_cast<short4v*>((unsigned short*)outp + n * rsout + obase) = pk;
      } else if (EPI == 2) {
        int nn = (int)(n & 16383);
        short4v pk;
#pragma unroll
        for (int r = 0; r < 4; r++) {
          float rx = residF[(((size_t)(b * 192 + obase + r)) << 14) + nn];
          pk[r] = (short)f2bf(rx + acc[nb][r]);
        }
        *reinterpret_cast<short4v*>((unsigned short*)outp + n * 192 + obase) = pk;
      } else {   // EPI == 3
        int nn = (int)(n & 16383);
        short4v rb = *reinterpret_cast<const short4v*>(residB + n * 192 + obase);
#pragma unroll
        for (int r = 0; r < 4; r++) {
          size_t idx = (((size_t)(b * 192 + obase + r)) << 14) + nn;
          ((float*)outp)[idx] = bf2f((unsigned short)rb[r]) + acc[nb][r];
        }
      }
    }
  }
}

// ---------------------------------------------------------------------------
// Depthwise 3x3 (pad 1), DIRECT (no LDS, no barrier). Thread = (b,h,2w,4ch).
// Loads: per set, 12 independent b64 chunks (3 rows x [w-1..w+2]); row addr
// clamped + value select-zeroed at edges; weights from packed fp32 blobs
// ([g][9][4], L1-resident). Lanes consecutive in ch-group -> coalesced taps.
//  FUSE=0: in [N][576] -> out [N][576], wp = dwq[144][9][4]
//  FUSE=1: in [N][1024] cols c & 512+c -> gelu(d1)*d2 -> out [N][512],
//          wp = dwf[2][128][9][4]
// ---------------------------------------------------------------------------
template <int FUSE>
__global__ __launch_bounds__(256) void k_dwconv2(
    const unsigned short* __restrict__ in, const float* __restrict__ wp,
    unsigned short* __restrict__ out) {
  constexpr int NG = FUSE ? 128 : 144;
  constexpr int RSI = FUSE ? 1024 : 576;
  constexpr int RSO = FUSE ? 512 : 576;
  constexpr int SETS = FUSE ? 2 : 1;
  int idx = blockIdx.x * 256 + threadIdx.x;
  int g = idx % NG;
  int rest = idx / NG;                 // (b,h,w2): 4*128*64
  int w2 = rest & 63;
  int h = (rest >> 6) & 127;
  int b = rest >> 13;
  int w0 = w2 * 2;
  int ch0 = g * 4;
  bool zm = (w0 == 0), zp = (w0 == 126);
  int offm = zm ? 0 : -RSI;
  int offp = zp ? RSI : 2 * RSI;

  float a1[2][4] = {{0.f,0.f,0.f,0.f},{0.f,0.f,0.f,0.f}};
  float a2[2][4] = {{0.f,0.f,0.f,0.f},{0.f,0.f,0.f,0.f}};

#pragma unroll
  for (int s = 0; s < SETS; s++) {
    int colb = (FUSE && s) ? 512 + ch0 : ch0;
    // issue all 12 loads (clamped rows), then zero-select
    short4v m[3][4];
    bool zh[3];
#pragma unroll
    for (int dh = 0; dh < 3; dh++) {
      int hh = h + dh - 1;
      zh[dh] = (unsigned)hh > 127u;
      int hc = zh[dh] ? h : hh;
      const unsigned short* p = in + (((size_t)b << 14) + hc * 128 + w0) * RSI + colb;
      m[dh][0] = *reinterpret_cast<const short4v*>(p + offm);
      m[dh][1] = *reinterpret_cast<const short4v*>(p);
      m[dh][2] = *reinterpret_cast<const short4v*>(p + RSI);
      m[dh][3] = *reinterpret_cast<const short4v*>(p + offp);
    }
    const short4v z4 = {0, 0, 0, 0};
#pragma unroll
    for (int dh = 0; dh < 3; dh++) {
      if (zh[dh]) { m[dh][0] = z4; m[dh][1] = z4; m[dh][2] = z4; m[dh][3] = z4; }
      else {
        if (zm) m[dh][0] = z4;
        if (zp) m[dh][3] = z4;
      }
    }
#pragma unroll
    for (int dh = 0; dh < 3; dh++) {
      float f[4][4];
#pragma unroll
      for (int k = 0; k < 4; k++)
#pragma unroll
        for (int j = 0; j < 4; j++) f[k][j] = bf2f((unsigned short)m[dh][k][j]);
#pragma unroll
      for (int dw = 0; dw < 3; dw++) {
        f32x4 wv = *reinterpret_cast<const f32x4*>(
            &wp[(((s * NG + g) * 9) + dh * 3 + dw) * 4]);
#pragma unroll
        for (int j = 0; j < 4; j++) {
          if (s == 0) {
            a1[0][j] += wv[j] * f[dw][j];
            a1[1][j] += wv[j] * f[dw + 1][j];
          } else {
            a2[0][j] += wv[j] * f[dw][j];
            a2[1][j] += wv[j] * f[dw + 1][j];
          }
        }
      }
    }
  }

  unsigned short* ob = out + (((size_t)b << 14) + h * 128 + w0) * RSO + ch0;
#pragma unroll
  for (int wout = 0; wout < 2; wout++) {
    short4v o4;
#pragma unroll
    for (int j = 0; j < 4; j++) {
      float val;
      if (FUSE) {
        float x1 = a1[wout][j];
        float gl = 0.5f * x1 * (1.f + erff(x1 * 0.70710678118654752f));
        val = gl * a2[wout][j];
      } else {
        val = a1[wout][j];
      }
      o4[j] = (short)f2bf(val);
    }
    *reinterpret_cast<short4v*>(ob + wout * RSO) = o4;
  }
}

// ---------------------------------------------------------------------------
// Gram: G[b][h][48][48] += stacked.stacked^T (rows [q_h;k_h]), over n.
// ---------------------------------------------------------------------------
__global__ __launch_bounds__(256) void k_gram(
    const unsigned short* __restrict__ qkvd, float* __restrict__ G) {
  constexpr int RS = 264;
  __shared__ unsigned short lds[48 * RS];
  int t = threadIdx.x;
  int nsp = blockIdx.x, h = blockIdx.y, b = blockIdx.z;
  int lane = t & 63, wv = t >> 6, lrow = lane & 15, lhi = lane >> 4;
  f32x4 D00 = {0.f,0.f,0.f,0.f}, D01 = D00, D02 = D00, D11 = D00, D12 = D00, D22 = D00;
  size_t rb = (size_t)b << 14;
  int qb = h * 24, kb = 192 + h * 24;

  for (int rnd = 0; rnd < 4; ++rnd) {
    int n0 = nsp * 1024 + rnd * 256;
    __syncthreads();
#pragma unroll
    for (int part = 0; part < 2; part++) {
      int cb = part ? kb : qb;
#pragma unroll
      for (int ch8 = 0; ch8 < 3; ch8++) {
        short8 v = *reinterpret_cast<const short8*>(
            &qkvd[(rb + n0 + t) * 576 + cb + ch8 * 8]);
#pragma unroll
        for (int j = 0; j < 8; j++)
          lds[(part * 24 + ch8 * 8 + j) * RS + t] = (unsigned short)v[j];
      }
    }
    __syncthreads();
#pragma unroll
    for (int st = 0; st < 2; st++) {
      int noff = (wv * 2 + st) * 32 + lhi * 8;
      short8 f0 = *reinterpret_cast<const short8*>(&lds[(0 + lrow) * RS + noff]);
      short8 f1 = *reinterpret_cast<const short8*>(&lds[(16 + lrow) * RS + noff]);
      short8 f2 = *reinterpret_cast<const short8*>(&lds[(32 + lrow) * RS + noff]);
      D00 = __builtin_amdgcn_mfma_f32_16x16x32_bf16(f0, f0, D00, 0, 0, 0);
      D01 = __builtin_amdgcn_mfma_f32_16x16x32_bf16(f0, f1, D01, 0, 0, 0);
      D02 = __builtin_amdgcn_mfma_f32_16x16x32_bf16(f0, f2, D02, 0, 0, 0);
      D11 = __builtin_amdgcn_mfma_f32_16x16x32_bf16(f1, f1, D11, 0, 0, 0);
      D12 = __builtin_amdgcn_mfma_f32_16x16x32_bf16(f1, f2, D12, 0, 0, 0);
      D22 = __builtin_amdgcn_mfma_f32_16x16x32_bf16(f2, f2, D22, 0, 0, 0);
    }
  }
  float* Gh = G + (size_t)(b * 8 + h) * 48 * 48;
#define EMIT(Dv, i, j)                                                          \
  {                                                                             \
    _Pragma("unroll") for (int r = 0; r < 4; r++)                               \
        atomicAdd(&Gh[(16 * (i) + lhi * 4 + r) * 48 + 16 * (j) + lrow], Dv[r]); \
  }
  EMIT(D00, 0, 0); EMIT(D01, 0, 1); EMIT(D02, 0, 2);
  EMIT(D11, 1, 1); EMIT(D12, 1, 2); EMIT(D22, 2, 2);
#undef EMIT
}

// ---------------------------------------------------------------------------
// softmax of logits built from Gram; A[b][h][c][d]
// ---------------------------------------------------------------------------
__global__ __launch_bounds__(256) void k_attnsm(
    const float* __restrict__ G, const float* __restrict__ temp,
    float* __restrict__ A) {
  int idx = blockIdx.x * 256 + threadIdx.x;   // 768
  if (idx >= 4 * 8 * 24) return;
  int b = idx / (8 * 24);
  int rem = idx - b * 8 * 24;
  int h = rem / 24, c = rem % 24;
  const float* Gh = G + (size_t)(b * 8 + h) * 48 * 48;
  float tpr = temp[h];
  float nq = fmaxf(sqrtf(fmaxf(Gh[c * 48 + c], 0.f)), 1e-12f);
  float lg[24];
  float mx = -1e30f;
#pragma unroll
  for (int d = 0; d < 24; d++) {
    float nk = fmaxf(sqrtf(fmaxf(Gh[(24 + d) * 48 + 24 + d], 0.f)), 1e-12f);
    float l = Gh[c * 48 + 24 + d] / (nq * nk) * tpr;
    lg[d] = l;
    mx = fmaxf(mx, l);
  }
  float s = 0.f;
#pragma unroll
  for (int d = 0; d < 24; d++) { lg[d] = expf(lg[d] - mx); s += lg[d]; }
  float inv = 1.f / s;
  float* Ar = A + (size_t)idx * 24;
#pragma unroll
  for (int d = 0; d < 24; d++) Ar[d] = lg[d] * inv;
}

// ---------------------------------------------------------------------------
// Fold proj_w with per-head attention: M[b][o][h*24+d] (bf16)
// ---------------------------------------------------------------------------
__global__ __launch_bounds__(256) void k_foldM(
    const float* __restrict__ A, const float* __restrict__ P,
    unsigned short* __restrict__ M) {
  int idx = blockIdx.x * 256 + threadIdx.x;   // 4*192*192
  if (idx >= 4 * 192 * 192) return;
  int b = idx / (192 * 192);
  int rem = idx - b * 192 * 192;
  int o = rem / 192, cd = rem % 192;
  int h = cd / 24, d = cd % 24;
  const float* Ah = A + (size_t)(b * 8 + h) * 24 * 24;
  const float* Pr = P + o * 192 + h * 24;
  float s = 0.f;
#pragma unroll
  for (int ch = 0; ch < 24; ch++) s += Pr[ch] * Ah[ch * 24 + d];
  M[idx] = f2bf(s);
}

// ---------------------------------------------------------------------------
extern "C" void kernel_launch(void* const* d_in, const int* in_sizes, int n_in,
                              void* d_out, int out_size, void* d_ws,
                              size_t ws_size, hipStream_t stream) {
  const float* x          = (const float*)d_in[0];
  const float* ln2_w      = (const float*)d_in[1];
  const float* ln2_b      = (const float*)d_in[2];
  const float* qkv_w      = (const float*)d_in[3];
  const float* qkv_dw_w   = (const float*)d_in[4];
  const float* temperature= (const float*)d_in[5];
  const float* attn_proj_w= (const float*)d_in[6];
  const float* ln3_w      = (const float*)d_in[7];
  const float* ln3_b      = (const float*)d_in[8];
  const float* ffn_in_w   = (const float*)d_in[9];
  const float* ffn_dw_w   = (const float*)d_in[10];
  const float* ffn_out_w  = (const float*)d_in[11];

  unsigned char* ws = (unsigned char*)d_ws;
  size_t off = 0;
  auto alloc = [&](size_t bytes) -> void* {
    void* p = ws + off;
    off = (off + bytes + 255) & ~(size_t)255;
    return p;
  };
  // S1: qkv [B][N][576] -> h [B][N][1024]
  // S2: y [B][N][192] -> qkvd [B][N][576] -> y3 [B][N][192] -> g [B][N][512]
  unsigned short* S1   = (unsigned short*)alloc(134217728); // 4*16384*1024*2
  unsigned short* S2   = (unsigned short*)alloc(75497472);  // 4*16384*576*2
  unsigned short* out1b= (unsigned short*)alloc(25165824);  // 4*16384*192*2
  unsigned short* wq   = (unsigned short*)alloc(221184);
  unsigned short* wi   = (unsigned short*)alloc(393216);
  unsigned short* wo   = (unsigned short*)alloc(196608);
  unsigned short* Mw   = (unsigned short*)alloc(294912);
  float*          G    = (float*)alloc(294912);
  float*          Aat  = (float*)alloc(73728);
  float*          dwq  = (float*)alloc(20736);              // 144*9*4*4
  float*          dwf  = (float*)alloc(36864);              // 2*128*9*4*4

  k_convert_w<<<768, 256, 0, stream>>>(qkv_w, ffn_in_w, ffn_out_w, qkv_dw_w,
                                       ffn_dw_w, wq, wi, wo, dwq, dwf);
  k_zero<<<288, 256, 0, stream>>>(G, 4 * 8 * 48 * 48);

  // K1: LN2(x) -> y bf16 [B][N][192] (S2)
  k_ln<<<512, 256, 0, stream>>>(x, ln2_w, ln2_b, S2);

  // K2: qkv = y @ wq^T -> S1 [B][N][576]
  k_gemm<192, 192, 2, 0><<<dim3(64, 3, 4), 512, 0, stream>>>(
      S2, 192, wq, 0, nullptr, nullptr, S1, 576);

  // K3: dwconv on qkv -> qkvd (S2)
  k_dwconv2<0><<<18432, 256, 0, stream>>>(S1, dwq, S2);

  // K4: Gram of [q;k] -> G
  k_gram<<<dim3(16, 8, 4), 256, 0, stream>>>(S2, G);

  // K5: softmax -> Aat ; fold with proj -> M
  k_attnsm<<<3, 256, 0, stream>>>(G, temperature, Aat);
  k_foldM<<<576, 256, 0, stream>>>(Aat, attn_proj_w, Mw);

  // K6: out1b = bf16(x + M[b] @ v)  (v = qkvd cols 384..575)
  k_gemm<192, 192, 2, 2><<<dim3(64, 1, 4), 512, 0, stream>>>(
      S2 + 384, 576, Mw, 192 * 192, x, nullptr, out1b, 192);

  // K7: LN3(out1b) -> y3 bf16 [B][N][192] (S2, qkvd dead)
  k_ln_bf<<<256, 256, 0, stream>>>(out1b, ln3_w, ln3_b, S2);

  // K8: h = y3 @ wi^T -> S1 [B][N][1024]
  k_gemm<192, 128, 2, 0><<<dim3(64, 8, 4), 512, 0, stream>>>(
      S2, 192, wi, 0, nullptr, nullptr, S1, 1024);

  // K9: dwconv pairs + gelu gate -> g [B][N][512] (S2)
  k_dwconv2<1><<<16384, 256, 0, stream>>>(S1, dwf, S2);

  // K10: d_out = out1b + g @ wo^T  (fp32 [B][192][N])
  k_gemm<512, 64, 1, 3><<<dim3(128, 3, 4), 512, 0, stream>>>(
      S2, 512, wo, 0, nullptr, out1b, d_out, 0);
}